// Round 20
// baseline (94.936 us; speedup 1.0000x reference)
//
#include <hip/hip_runtime.h>

// ---------------------------------------------------------------------------
// DWT autoencoder round trip. Level-2 dwt2+idwt2 cancel exactly -> LL1r==LL1.
//   K0: rearrange conv weights into consumption order
//   K1: R18 skeleton (band planes in 20.2KB LDS, one barrier, og-split conv)
//       with conv LDS reads PAIRED (ds_read2): 54 LDS instr/thread vs 81.
//       Theory: ~81 scalar ds_read_b32 x 5.8cyc x 64 waves/CU ~ 12us of LDS
//       issue is the largest untouched slice of k1's 57us.
//   K2: convT4x4 s2 of y -> l1 bands, fused with idwt2(LL1, l1) -> out
//       (same paired-read treatment, 6 vs 9 per cin).
// B=32, C=3, H=W=512.
// ---------------------------------------------------------------------------

#define BB 32

// K0: wd[(cin*9 + a*3 + q)*9 + o] = 0.5 * dw[o, cin, a, q]   (cin = ch*3+band)
//     wu[((cin*4+rt*2+ct)*4+di*2+dj)*9+o] = uw[cin, o, 3-di-2rt, 3-dj-2ct]
__global__ __launch_bounds__(256) void k0_rearrange(
    const float* __restrict__ dw, const float* __restrict__ uw,
    float* __restrict__ wd, float* __restrict__ wu)
{
    const int t = threadIdx.x;
    for (int i = t; i < 729; i += 256) {
        const int o   = i % 9;
        const int q   = (i / 9) % 3;
        const int a   = (i / 27) % 3;
        const int cin = i / 81;
        wd[i] = 0.5f * dw[o * 81 + cin * 9 + a * 3 + q];
    }
    for (int i = t; i < 1296; i += 256) {
        const int o = i % 9; int r = i / 9;
        const int dj = r & 1; const int di = (r >> 1) & 1; r >>= 2;
        const int ct = r & 1; const int rt = (r >> 1) & 1; const int cin = r >> 2;
        wu[i] = uw[cin * 144 + o * 16 + (3 - di - 2 * rt) * 4 + (3 - dj - 2 * ct)];
    }
}

// K1: block = 8x16 y-tile. Stage: 1683 items (3ch x 17x33 band grid), each
// reads a 2x2 x-block (two float2, coalesced over lc), writes 3 band planes
// to LDS + owned LL1 interior. One barrier. Conv: og wave-split (o0-4/o5-8);
// window reads paired: per (cin,a) one float2 (cols 2tj,2tj+1) + one float2
// (cols 2tj+2,2tj+3, x element unused) -> ds_read2, 6 instr/cin.
__global__ __launch_bounds__(256) void k1_dwt_down(
    const float* __restrict__ x,     // (B,3,512,512)
    const float* __restrict__ wd,    // reordered (cin,a,q,o), x0.5 folded
    const float* __restrict__ db,    // (9)
    float* __restrict__ LL1,         // (B,3,256,256)
    float* __restrict__ y)           // (B,9,128,128)
{
    __shared__ float bnd[9 * 561];   // plane (ch*3+band): 17 x 33, 20.2 KB

    const int t   = threadIdx.x;
    const int bid = blockIdx.x;                     // 0..4095
    const int swz = (bid & 7) * 512 + (bid >> 3);   // XCD-contiguous chunks
    const int b   = swz >> 7;                       // image 0..31
    const int tin = swz & 127;
    const int I0  = (tin >> 3) * 8;                 // y row origin (0..120)
    const int J0  = (tin & 7) * 16;                 // y col origin (0..112)

    // ---- stage: bands + LL1 (plain coalesced loads) ----
    for (int it = t; it < 1683; it += 256) {
        const int ch = it / 561;
        const int rc = it - ch * 561;
        const int lr = rc / 33;                     // 0..16
        const int lc = rc - lr * 33;                // 0..32
        const int rB = 2 * I0 - 1 + lr;             // band row, -1..254
        const int cB = 2 * J0 - 1 + lc;             // band col, -1..254
        float x00 = 0.f, x01 = 0.f, x10 = 0.f, x11 = 0.f;
        if (rB >= 0 && cB >= 0) {
            const float* xp =
                x + (((size_t)b * 3 + ch) * 512 + 2 * rB) * 512 + 2 * cB;
            const float2 v0 = *reinterpret_cast<const float2*>(xp);
            const float2 v1 = *reinterpret_cast<const float2*>(xp + 512);
            x00 = v0.x; x01 = v0.y; x10 = v1.x; x11 = v1.y;
        }
        const float s0 = x00 + x01, d0 = x00 - x01;
        const float s1 = x10 + x11, d1 = x10 - x11;
        bnd[(ch * 3 + 0) * 561 + lr * 33 + lc] = s0 - s1;   // lh
        bnd[(ch * 3 + 1) * 561 + lr * 33 + lc] = d0 + d1;   // hl
        bnd[(ch * 3 + 2) * 561 + lr * 33 + lc] = d0 - d1;   // hh
        if (lr >= 1 && lc >= 1)
            LL1[(((size_t)b * 3 + ch) * 256 + rB) * 256 + cB] = (s0 + s1) * 0.5f;
    }
    __syncthreads();

    // ---- conv: og-split, paired LDS reads ----
    const int og = t >> 7;           // wave-uniform output half
    const int tl = t & 127;
    const int ti = tl >> 4;          // 0..7
    const int tj = tl & 15;          // 0..15
    const int I  = I0 + ti;
    const int J  = J0 + tj;

    if (og == 0) {
        float acc[5];
#pragma unroll
        for (int o = 0; o < 5; ++o) acc[o] = db[o];
        for (int cin = 0; cin < 9; ++cin) {
            float v[3][3];
#pragma unroll
            for (int a = 0; a < 3; ++a) {
                const float* rp = &bnd[cin * 561 + (2 * ti + a) * 33 + 2 * tj];
                const float2 p0 = *reinterpret_cast<const float2*>(rp);
                const float2 p1 = *reinterpret_cast<const float2*>(rp + 2);
                v[a][0] = p0.x; v[a][1] = p0.y; v[a][2] = p1.x;
            }
            const float* wc = wd + cin * 81;
#pragma unroll
            for (int a = 0; a < 3; ++a)
#pragma unroll
                for (int q = 0; q < 3; ++q) {
                    const float vv = v[a][q];
                    const float* w9 = wc + (a * 3 + q) * 9;
#pragma unroll
                    for (int o = 0; o < 5; ++o) acc[o] += vv * w9[o];
                }
        }
#pragma unroll
        for (int o = 0; o < 5; ++o)
            y[(((size_t)b * 9 + o) * 128 + I) * 128 + J] = acc[o];
    } else {
        float acc[4];
#pragma unroll
        for (int o = 0; o < 4; ++o) acc[o] = db[5 + o];
        for (int cin = 0; cin < 9; ++cin) {
            float v[3][3];
#pragma unroll
            for (int a = 0; a < 3; ++a) {
                const float* rp = &bnd[cin * 561 + (2 * ti + a) * 33 + 2 * tj];
                const float2 p0 = *reinterpret_cast<const float2*>(rp);
                const float2 p1 = *reinterpret_cast<const float2*>(rp + 2);
                v[a][0] = p0.x; v[a][1] = p0.y; v[a][2] = p1.x;
            }
            const float* wc = wd + cin * 81;
#pragma unroll
            for (int a = 0; a < 3; ++a)
#pragma unroll
                for (int q = 0; q < 3; ++q) {
                    const float vv = v[a][q];
                    const float* w9 = wc + (a * 3 + q) * 9 + 5;
#pragma unroll
                    for (int o = 0; o < 4; ++o) acc[o] += vv * w9[o];
                }
        }
#pragma unroll
        for (int o = 0; o < 4; ++o)
            y[(((size_t)b * 9 + 5 + o) * 128 + I) * 128 + J] = acc[o];
    }
}

// K2: one block = one batch image, a 32x32 tile at 256-res (=> 64x64 output
// pixels at 512-res), all 3 colors. Each thread owns a 2x2 parity quad; all
// 36 accumulators live (needs VGPR room -> launch_bounds(256,4)).
// Window reads paired: float2 (c=0,1) + scalar (c=2) per row.
__global__ __launch_bounds__(256, 4) void k2_up_idwt(
    const float* __restrict__ yg,    // (B,9,128,128)
    const float* __restrict__ wu,    // reordered (cin,rt,ct,di,dj,o)
    const float* __restrict__ ub,    // (9)
    const float* __restrict__ LL1,   // (B,3,256,256)
    float* __restrict__ out)         // (B,3,512,512)
{
    __shared__ float ysh[9][18][19];

    const int t    = threadIdx.x;
    const int b    = blockIdx.x >> 6;
    const int tile = blockIdx.x & 63;
    const int r0   = (tile >> 3) << 5;  // 256-res tile origin
    const int c0   = (tile & 7) << 5;
    const int p0   = (r0 >> 1) - 1;     // y row of local 0
    const int q0   = (c0 >> 1) - 1;

    // ---- stage y tile (18x18 halo, 9 ch) into LDS ----
    for (int item = t; item < 9 * 324; item += 256) {
        const int cin = item / 324;
        int rem       = item - cin * 324;
        const int lp  = rem / 18;
        const int lq  = rem - lp * 18;
        const int p   = p0 + lp, q = q0 + lq;
        float v = 0.f;
        if (p >= 0 && p < 128 && q >= 0 && q < 128)
            v = yg[(((size_t)b * 9 + cin) * 128 + p) * 128 + q];
        ysh[cin][lp][lq] = v;
    }
    __syncthreads();

    const int i2 = t >> 4;   // 0..15
    const int j2 = t & 15;   // 0..15

    float acc[2][2][9];      // [di][dj][out-ch]
#pragma unroll
    for (int di = 0; di < 2; ++di)
#pragma unroll
        for (int dj = 0; dj < 2; ++dj)
#pragma unroll
            for (int o = 0; o < 9; ++o) acc[di][dj][o] = ub[o];

    for (int cin = 0; cin < 9; ++cin) {
        float yv[3][3];
#pragma unroll
        for (int r = 0; r < 3; ++r) {
            const float* rp = &ysh[cin][i2 + r][j2];
            const float2 p0v = *reinterpret_cast<const float2*>(rp);
            yv[r][0] = p0v.x; yv[r][1] = p0v.y; yv[r][2] = rp[2];
        }
        const float* wc = wu + cin * 144;
#pragma unroll
        for (int rt = 0; rt < 2; ++rt)
#pragma unroll
            for (int ct = 0; ct < 2; ++ct) {
                const float* wg = wc + (rt * 2 + ct) * 36;  // 36 consecutive
#pragma unroll
                for (int di = 0; di < 2; ++di)
#pragma unroll
                    for (int dj = 0; dj < 2; ++dj) {
                        const float vv = yv[di + rt][dj + ct];
                        const float* w9 = wg + (di * 2 + dj) * 9;
#pragma unroll
                        for (int o = 0; o < 9; ++o)
                            acc[di][dj][o] += vv * w9[o];
                    }
            }
    }

    // ---- epilogue: idwt2(LL1, LH, HL, HH) -> 4x4 output pixels / color ----
#pragma unroll
    for (int cc = 0; cc < 3; ++cc) {
#pragma unroll
        for (int di = 0; di < 2; ++di) {
            const int I = r0 + 2 * i2 + di;
            const int J = c0 + 2 * j2;
            const float2 llv = *reinterpret_cast<const float2*>(
                LL1 + (((size_t)b * 3 + cc) * 256 + I) * 256 + J);
            float4 top, bot;
            {
                const float ll = llv.x;
                const float lh = acc[di][0][cc * 3 + 0];
                const float hl = acc[di][0][cc * 3 + 1];
                const float hh = acc[di][0][cc * 3 + 2];
                const float e0 = ll + lh, od0 = ll - lh;
                const float e1 = hl + hh, od1 = hl - hh;
                top.x = (e0 + e1) * 0.5f; top.y = (e0 - e1) * 0.5f;
                bot.x = (od0 + od1) * 0.5f; bot.y = (od0 - od1) * 0.5f;
            }
            {
                const float ll = llv.y;
                const float lh = acc[di][1][cc * 3 + 0];
                const float hl = acc[di][1][cc * 3 + 1];
                const float hh = acc[di][1][cc * 3 + 2];
                const float e0 = ll + lh, od0 = ll - lh;
                const float e1 = hl + hh, od1 = hl - hh;
                top.z = (e0 + e1) * 0.5f; top.w = (e0 - e1) * 0.5f;
                bot.z = (od0 + od1) * 0.5f; bot.w = (od0 - od1) * 0.5f;
            }
            float* op = out + (((size_t)b * 3 + cc) * 512 + 2 * I) * 512 + 2 * J;
            *reinterpret_cast<float4*>(op) = top;
            *reinterpret_cast<float4*>(op + 512) = bot;
        }
    }
}

extern "C" void kernel_launch(void* const* d_in, const int* in_sizes, int n_in,
                              void* d_out, int out_size, void* d_ws, size_t ws_size,
                              hipStream_t stream) {
    const float* x  = (const float*)d_in[0];
    const float* dw = (const float*)d_in[1];
    const float* db = (const float*)d_in[2];
    const float* uw = (const float*)d_in[3];
    const float* ub = (const float*)d_in[4];
    float* outp = (float*)d_out;

    float* wsf = (float*)d_ws;
    float* wd  = wsf;            // 729 floats (pad to 768)
    float* wu  = wsf + 768;      // 1296 floats
    float* LL1 = wsf + 2304;                         // 25.2 MB
    float* y   = LL1 + (size_t)BB * 3 * 256 * 256;   // 18.9 MB

    k0_rearrange<<<dim3(1), dim3(256), 0, stream>>>(dw, uw, wd, wu);
    k1_dwt_down<<<dim3(4096), dim3(256), 0, stream>>>(x, wd, db, LL1, y);
    k2_up_idwt<<<dim3(BB * 64), dim3(256), 0, stream>>>(y, wu, ub, LL1, outp);
}